// Round 11
// baseline (123.536 us; speedup 1.0000x reference)
//
#include <hip/hip_runtime.h>
#include <hip/hip_bf16.h>
#include <math.h>

// HGCN decoder, B=512, N=128, D=256, F=16, L=3, c=1 Poincare ball.
// R11: LDS-read reduction with phase-disjoint register budgets.
//  - GEMM-a 16x16x32, wave = (m-half mh) x (n-pair nc8): 4 m-tiles x 2
//    n-tiles; each sT A-read feeds 2 MFMAs -> 512 A-reads/block/layer
//    (was 1024). B = 16 Wt frags (64 VGPR) live ONLY during GEMM-a,
//    prefetched one full phase ahead (layer L+1's frags load right after
//    GEMM-b's MFMAs; layer-2 slot loads the head's WoutT frags).
//  - adjf (32 VGPR) reloaded per layer (L2-hot), issued right after
//    GEMM-a's MFMAs, consumed after epi-a + barrier.
//  - GEMM-b/epi-b: R9-verified 32x32 blocks (256 A-reads).
// Padded-linear LDS (row stride % 32 words == 4), cvt_pkrtz packing.

typedef _Float16 f16;
typedef f16 f16x8 __attribute__((ext_vector_type(8)));
typedef f16 f16x4 __attribute__((ext_vector_type(4)));
typedef f16 f16x2 __attribute__((ext_vector_type(2)));
typedef __fp16 fp16x2_cv __attribute__((ext_vector_type(2)));
typedef float f32x4 __attribute__((ext_vector_type(4)));
typedef float f32x16 __attribute__((ext_vector_type(16)));

#define NB 512
#define NN 128
#define ND 256
#define NF 16
#define NL 3

#define SDT 264   // sT row stride f16: 528B = 132 words, %32 = 4
#define SDV 136   // sV row stride f16: 272B =  68 words, %32 = 4

#define EPSV   1e-7f
#define MAXN   0.99999f      // 1 - 1e-5
#define ATHMAX 6.1030340f    // atanh(1 - 1e-5)

__device__ __forceinline__ f16x4 pack4(float a, float b, float c, float d) {
    fp16x2_cv lo = __builtin_amdgcn_cvt_pkrtz(a, b);
    fp16x2_cv hi = __builtin_amdgcn_cvt_pkrtz(c, d);
    f16x2 lo2, hi2;
    __builtin_memcpy(&lo2, &lo, sizeof(lo2));
    __builtin_memcpy(&hi2, &hi, sizeof(hi2));
    return __builtin_shufflevector(lo2, hi2, 0, 1, 2, 3);
}

// One-time: Wt[l][n][k] = W[l][k][n] (f16), WoutT[f][k] = Wout[k][f] (f16).
__global__ void prep_kernel(const float* __restrict__ Ws,
                            const float* __restrict__ Wout,
                            f16* __restrict__ Wt, f16* __restrict__ WoutT) {
    int idx = blockIdx.x * 256 + threadIdx.x;
    if (idx < NL * ND * ND) {
        int l = idx / (ND * ND);
        int r = idx % (ND * ND);
        int n = r >> 8;
        int k = r & 255;
        Wt[idx] = (f16)Ws[l * ND * ND + k * ND + n];
    }
    if (idx < NF * ND) {
        int f = idx >> 8;
        int k = idx & 255;
        WoutT[idx] = (f16)Wout[k * NF + f];
    }
}

__global__ __launch_bounds__(1024, 4)
void hgcn_kernel(const float* __restrict__ x,
                 const float* __restrict__ adj,
                 const float* __restrict__ node_mask,
                 const f16*  __restrict__ Wt,
                 const float* __restrict__ bs,
                 const f16*  __restrict__ WoutT,
                 const float* __restrict__ bout,
                 float* __restrict__ out) {
    __shared__ __align__(16) f16 sT[NN * SDT];   // [node m][feat k] 66KB
    __shared__ __align__(16) f16 sV[ND * SDV];   // [feat n][node m] 68KB
    __shared__ __align__(16) float sRed[NN * 4]; // 4 partials per node 2KB

    const int b    = blockIdx.x;
    const int tid  = threadIdx.x;
    const int wave = tid >> 6;   // 0..15
    const int lane = tid & 63;
    const int l31  = lane & 31;
    const int hi   = lane >> 5;  // k-half for 32x32x16 fragments
    const int lg   = lane >> 4;
    const int lc   = lane & 15;

    // GEMM-a roles (16x16): m-half mh (4 m-tiles), n-pair nc8 (2 n-tiles).
    const int mh  = wave >> 3;   // 0..1
    const int nc8 = wave & 7;    // 0..7
    // GEMM-b roles (32x32): i-col ic, n-tile pair {2*nr2, 2*nr2+1}.
    const int nr2 = wave >> 2;   // 0..3
    const int ic  = wave & 3;    // 0..3

    const f32x16 fzero16 = {0.f};
    const float* adjb = adj + (size_t)b * NN * NN;

    // ---------- GEMM-a B fragments for layer 0 (consumed after init) -------
    // bf[nt][ks]: n = nc8*32 + nt*16 + lc, k = ks*32 + lg*8 .. +7.
    f16x8 bf[2][8];
    {
        const f16* w0 = Wt + (nc8 * 32 + 0 * 16 + lc) * ND + lg * 8;
        const f16* w1 = Wt + (nc8 * 32 + 1 * 16 + lc) * ND + lg * 8;
        #pragma unroll
        for (int ks = 0; ks < 8; ++ks) {
            bf[0][ks] = *(const f16x8*)(w0 + ks * 32);
            bf[1][ks] = *(const f16x8*)(w1 + ks * 32);
        }
    }

    // ---------- init: sT = f16(logmap0(proj(x[b]))), 8 rows per wave -------
    {
        const float4* xb = (const float4*)(x + (size_t)b * NN * ND);
        #pragma unroll
        for (int r = 0; r < 8; ++r) {
            int row = wave * 8 + r;
            float4 v = xb[row * 64 + lane];
            float ssq = v.x * v.x + v.y * v.y + v.z * v.z + v.w * v.w;
            #pragma unroll
            for (int d = 1; d < 64; d <<= 1) ssq += __shfl_xor(ssq, d);
            float norm = sqrtf(ssq);
            float sc1 = (norm > MAXN) ? (MAXN / norm) : 1.0f;      // proj
            float hn  = fmaxf(norm * sc1, EPSV);
            float aa  = fminf(hn, MAXN);
            float ath = 0.5f * __logf((1.0f + aa) / (1.0f - aa));  // atanh
            float s   = sc1 * ath / hn;                            // logmap0
            *(f16x4*)&sT[row * SDT + lane * 4] =
                pack4(v.x * s, v.y * s, v.z * s, v.w * s);
        }
    }
    __syncthreads();

    f16x8 adjf[8];

    for (int layer = 0; layer < NL; ++layer) {
        // ---- GEMM-a: V[m][n] = T @ W + b (16x16x32). 4 m-tiles x 2
        // n-tiles; A = sT row (LDS, each read feeds 2 MFMAs); B = bf (regs,
        // prefetched a full phase ago). Pure LDS+MFMA loop.
        f32x4 acc_a[4][2];
        #pragma unroll
        for (int mt = 0; mt < 4; ++mt)
            #pragma unroll
            for (int nt = 0; nt < 2; ++nt)
                acc_a[mt][nt] = (f32x4){0.f, 0.f, 0.f, 0.f};

        #pragma unroll
        for (int ks = 0; ks < 8; ++ks) {
            #pragma unroll
            for (int mt = 0; mt < 4; ++mt) {
                int row = mh * 64 + mt * 16 + lc;
                f16x8 afr = *(const f16x8*)&sT[row * SDT + ks * 32 + lg * 8];
                acc_a[mt][0] = __builtin_amdgcn_mfma_f32_16x16x32_f16(afr, bf[0][ks], acc_a[mt][0], 0, 0, 0);
                acc_a[mt][1] = __builtin_amdgcn_mfma_f32_16x16x32_f16(afr, bf[1][ks], acc_a[mt][1], 0, 0, 0);
            }
        }

        // ---- adjf for THIS layer's GEMM-b (bf is dead now; L2-hot after
        // layer 0). Consumed after epi-a + barrier.
        #pragma unroll
        for (int ks = 0; ks < 8; ++ks) {
            const float4* ap = (const float4*)(adjb + (ic * 32 + l31) * NN + ks * 16 + hi * 8);
            float4 alo = ap[0], ahi = ap[1];
            f16x4 l4 = pack4(alo.x, alo.y, alo.z, alo.w);
            f16x4 h4 = pack4(ahi.x, ahi.y, ahi.z, ahi.w);
            adjf[ks] = __builtin_shufflevector(l4, h4, 0, 1, 2, 3, 4, 5, 6, 7);
        }

        // epilogue-a: +bias, pack f16x4 (4 consecutive m), store sV[n][m].
        #pragma unroll
        for (int nt = 0; nt < 2; ++nt) {
            int n = nc8 * 32 + nt * 16 + lc;
            float bias = bs[layer * ND + n];
            #pragma unroll
            for (int mt = 0; mt < 4; ++mt) {
                int m0 = mh * 64 + mt * 16 + lg * 4;
                *(f16x4*)&sV[n * SDV + m0] =
                    pack4(acc_a[mt][nt][0] + bias, acc_a[mt][nt][1] + bias,
                          acc_a[mt][nt][2] + bias, acc_a[mt][nt][3] + bias);
            }
        }
        __syncthreads();

        // ---- GEMM-b: U^T[n][i] (32x32x16), R9-verified. 2 n-tiles x i-col.
        // A = sV row n (LDS), B = adjf (registers).
        f32x16 acc_b0 = fzero16, acc_b1 = fzero16;
        #pragma unroll
        for (int ks = 0; ks < 8; ++ks) {
            f16x8 a0 = *(const f16x8*)&sV[((2 * nr2 + 0) * 32 + l31) * SDV + ks * 16 + hi * 8];
            f16x8 a1 = *(const f16x8*)&sV[((2 * nr2 + 1) * 32 + l31) * SDV + ks * 16 + hi * 8];
            acc_b0 = __builtin_amdgcn_mfma_f32_32x32x16_f16(a0, adjf[ks], acc_b0, 0, 0, 0);
            acc_b1 = __builtin_amdgcn_mfma_f32_32x32x16_f16(a1, adjf[ks], acc_b1, 0, 0, 0);
        }

        // ---- prefetch next GEMM-a's B frags (adjf dead; consumed after
        // epi-b + 2 barriers). Layer-2 slot loads the head's WoutT frags.
        if (layer + 1 < NL) {
            const f16* w0 = Wt + (layer + 1) * ND * ND + (nc8 * 32 + 0 * 16 + lc) * ND + lg * 8;
            const f16* w1 = Wt + (layer + 1) * ND * ND + (nc8 * 32 + 1 * 16 + lc) * ND + lg * 8;
            #pragma unroll
            for (int ks = 0; ks < 8; ++ks) {
                bf[0][ks] = *(const f16x8*)(w0 + ks * 32);
                bf[1][ks] = *(const f16x8*)(w1 + ks * 32);
            }
        } else {
            const f16* wh = WoutT + lc * ND + lg * 8;
            #pragma unroll
            for (int ks = 0; ks < 8; ++ks)
                bf[0][ks] = *(const f16x8*)(wh + ks * 32);
        }

        // ---- epilogue-b (R9-verified): relu + node-norm partials.
        float ssq = 0.f;
        #pragma unroll
        for (int r = 0; r < 16; ++r) {
            float v0 = fmaxf(acc_b0[r], 0.0f);
            float v1 = fmaxf(acc_b1[r], 0.0f);
            acc_b0[r] = v0;
            acc_b1[r] = v1;
            ssq += v0 * v0 + v1 * v1;
        }
        ssq += __shfl_xor(ssq, 32);   // fold the two row-halves (same col i)
        if (lane < 32) sRed[(ic * 32 + l31) * 4 + nr2] = ssq;
        __syncthreads();

        f32x4 p = *(const f32x4*)&sRed[(ic * 32 + l31) * 4];
        float tot = p[0] + p[1] + p[2] + p[3];
        float nu = sqrtf(tot);
        float scale = (nu > ATHMAX) ? (ATHMAX / nu) : 1.0f;

        // fused logmap0(proj(expmap0(u))) = u * min(1, ATHMAX/||u||) -> sT.
        {
            int i = ic * 32 + l31;
            #pragma unroll
            for (int g = 0; g < 4; ++g) {
                int n0 = (2 * nr2 + 0) * 32 + 8 * g + 4 * hi;
                int n1 = (2 * nr2 + 1) * 32 + 8 * g + 4 * hi;
                *(f16x4*)&sT[i * SDT + n0] =
                    pack4(acc_b0[4 * g + 0] * scale, acc_b0[4 * g + 1] * scale,
                          acc_b0[4 * g + 2] * scale, acc_b0[4 * g + 3] * scale);
                *(f16x4*)&sT[i * SDT + n1] =
                    pack4(acc_b1[4 * g + 0] * scale, acc_b1[4 * g + 1] * scale,
                          acc_b1[4 * g + 2] * scale, acc_b1[4 * g + 3] * scale);
            }
        }
        __syncthreads();
    }

    // ---------- head: out = (out_tan @ Wout + bout) * node_mask ------------
    // B fragments already in bf[0] (prefetched from WoutT during layer 2).
    if (wave < 8) {
        f32x4 acc = {0.f, 0.f, 0.f, 0.f};
        #pragma unroll
        for (int ks = 0; ks < 8; ++ks) {
            f16x8 afr = *(const f16x8*)&sT[(wave * 16 + lc) * SDT + ks * 32 + lg * 8];
            acc = __builtin_amdgcn_mfma_f32_16x16x32_f16(afr, bf[0][ks], acc, 0, 0, 0);
        }
        #pragma unroll
        for (int r = 0; r < 4; ++r) {
            int row = wave * 16 + lg * 4 + r;
            float mask = node_mask[b * NN + row];
            out[((size_t)b * NN + row) * NF + lc] = (acc[r] + bout[lc]) * mask;
        }
    }
}

extern "C" void kernel_launch(void* const* d_in, const int* in_sizes, int n_in,
                              void* d_out, int out_size, void* d_ws, size_t ws_size,
                              hipStream_t stream) {
    const float* x    = (const float*)d_in[0];
    const float* adj  = (const float*)d_in[1];
    const float* mask = (const float*)d_in[2];
    const float* Ws   = (const float*)d_in[3];
    const float* bsp  = (const float*)d_in[4];
    const float* Wout = (const float*)d_in[5];
    const float* bout = (const float*)d_in[6];

    f16* Wt    = (f16*)d_ws;                       // 3*256*256 f16 = 384KB
    f16* WoutT = Wt + NL * ND * ND;                // 16*256 f16 = 8KB

    prep_kernel<<<768, 256, 0, stream>>>(Ws, Wout, Wt, WoutT);
    hgcn_kernel<<<NB, 1024, 0, stream>>>(x, adj, mask, Wt, bsp, WoutT, bout,
                                         (float*)d_out);
}

// Round 12
// 111.451 us; speedup vs baseline: 1.1084x; 1.1084x over previous
//
#include <hip/hip_runtime.h>
#include <hip/hip_bf16.h>
#include <math.h>

// HGCN decoder, B=512, N=128, D=256, F=16, L=3, c=1 Poincare ball.
// R12: COMMUTED layer structure U = (A*T)*W (adj constant across layers):
//   GEMM-1: S^T[k][i] = mfma(A = T^T rows k (LDS sTT), B = adjf registers)
//           -> 256 b128 LDS reads/block/layer (adjf loaded ONCE, R9 pattern)
//   GEMM-2: U^T[n][i] = mfma(A = Wt rows n (global, in-loop R6-style,
//           reused x2), B = S rows i (LDS sS)) -> 512 reads.
// Total LDS b128 reads/layer: 768 vs 1536 in the 78us R6 kernel.
// Bias commutes as rs_i * b_n (rs = adj row sums, computed once).
// Epilogue-2 writes T'^T[n][i] with coalesced ds_write_b16 (64 lanes =
// contiguous i). One-time transpose passes: init T -> sTT, final sTT -> sS
// for the (unchanged) head. 16 waves/block, 1 block = 1 batch.

typedef _Float16 f16;
typedef f16 f16x8 __attribute__((ext_vector_type(8)));
typedef f16 f16x4 __attribute__((ext_vector_type(4)));
typedef f16 f16x2 __attribute__((ext_vector_type(2)));
typedef __fp16 fp16x2_cv __attribute__((ext_vector_type(2)));
typedef float f32x4 __attribute__((ext_vector_type(4)));
typedef float f32x16 __attribute__((ext_vector_type(16)));

#define NB 512
#define NN 128
#define ND 256
#define NF 16
#define NL 3

#define SDS 264   // sS row stride f16 ([i 128][k]):  528B = 132 w, %8 = 4
#define SDJ 136   // sTT row stride f16 ([k 256][i]): 272B =  68 w, %8 = 4

#define EPSV   1e-7f
#define MAXN   0.99999f      // 1 - 1e-5
#define ATHMAX 6.1030340f    // atanh(1 - 1e-5)

__device__ __forceinline__ f16x4 pack4(float a, float b, float c, float d) {
    fp16x2_cv lo = __builtin_amdgcn_cvt_pkrtz(a, b);
    fp16x2_cv hi = __builtin_amdgcn_cvt_pkrtz(c, d);
    f16x2 lo2, hi2;
    __builtin_memcpy(&lo2, &lo, sizeof(lo2));
    __builtin_memcpy(&hi2, &hi, sizeof(hi2));
    return __builtin_shufflevector(lo2, hi2, 0, 1, 2, 3);
}

// One-time: Wt[l][n][k] = W[l][k][n] (f16), WoutT[f][k] = Wout[k][f] (f16).
__global__ void prep_kernel(const float* __restrict__ Ws,
                            const float* __restrict__ Wout,
                            f16* __restrict__ Wt, f16* __restrict__ WoutT) {
    int idx = blockIdx.x * 256 + threadIdx.x;
    if (idx < NL * ND * ND) {
        int l = idx / (ND * ND);
        int r = idx % (ND * ND);
        int n = r >> 8;
        int k = r & 255;
        Wt[idx] = (f16)Ws[l * ND * ND + k * ND + n];
    }
    if (idx < NF * ND) {
        int f = idx >> 8;
        int k = idx & 255;
        WoutT[idx] = (f16)Wout[k * NF + f];
    }
}

__global__ __launch_bounds__(1024, 4)
void hgcn_kernel(const float* __restrict__ x,
                 const float* __restrict__ adj,
                 const float* __restrict__ node_mask,
                 const f16*  __restrict__ Wt,
                 const float* __restrict__ bs,
                 const f16*  __restrict__ WoutT,
                 const float* __restrict__ bout,
                 float* __restrict__ out) {
    __shared__ __align__(16) f16 sS[NN * SDS];    // [node i][feat k] 67.6KB
    __shared__ __align__(16) f16 sTT[ND * SDJ];   // [feat k][node j] 69.6KB
    __shared__ __align__(16) float sRed[NN * 8];  // 8 norm partials/node 4KB
    __shared__ float sRs[NN];                     // adj row sums 0.5KB

    const int b    = blockIdx.x;
    const int tid  = threadIdx.x;
    const int wave = tid >> 6;   // 0..15
    const int lane = tid & 63;
    const int l31  = lane & 31;
    const int hi   = lane >> 5;  // k-half for 32x32x16 fragments
    const int lg   = lane >> 4;  // head (16x16) only
    const int lc   = lane & 15;

    // GEMM-1 roles: k-tile pair {2*kp, 2*kp+1}, i-col ic1 (adjf).
    const int kp  = wave >> 2;   // 0..3
    const int ic1 = wave & 3;    // 0..3
    // GEMM-2 roles: n-tile nt, i-col pair {2*ip, 2*ip+1}.
    const int nt  = wave >> 1;   // 0..7
    const int ip  = wave & 1;    // 0..1
    const int iA  = 64 * ip + l31;
    const int iB  = iA + 32;

    const f32x16 fzero16 = {0.f};
    const float* adjb = adj + (size_t)b * NN * NN;

    // ---------- adj B-fragments (32 VGPR, loaded ONCE, all 3 layers) -------
    // B[k=j][col=i] = adj[ic1*32+l31][j], j = ks*16 + hi*8 .. +7.
    f16x8 adjf[8];
    #pragma unroll
    for (int ks = 0; ks < 8; ++ks) {
        const float4* ap = (const float4*)(adjb + (ic1 * 32 + l31) * NN + ks * 16 + hi * 8);
        float4 alo = ap[0], ahi = ap[1];
        f16x4 l4 = pack4(alo.x, alo.y, alo.z, alo.w);
        f16x4 h4 = pack4(ahi.x, ahi.y, ahi.z, ahi.w);
        adjf[ks] = __builtin_shufflevector(l4, h4, 0, 1, 2, 3, 4, 5, 6, 7);
    }

    // ---------- adj row sums rs_i (for commuted bias), once ---------------
    #pragma unroll
    for (int rr = 0; rr < 8; ++rr) {
        int i = wave * 8 + rr;
        float s = adjb[i * NN + lane] + adjb[i * NN + 64 + lane];
        #pragma unroll
        for (int d = 1; d < 64; d <<= 1) s += __shfl_xor(s, d);
        if (lane == 0) sRs[i] = s;
    }

    // ---------- init: T = logmap0(proj(x[b])) -> sS[j][k] (row writes) -----
    {
        const float4* xb = (const float4*)(x + (size_t)b * NN * ND);
        #pragma unroll
        for (int r = 0; r < 8; ++r) {
            int row = wave * 8 + r;
            float4 v = xb[row * 64 + lane];
            float ssq = v.x * v.x + v.y * v.y + v.z * v.z + v.w * v.w;
            #pragma unroll
            for (int d = 1; d < 64; d <<= 1) ssq += __shfl_xor(ssq, d);
            float norm = sqrtf(ssq);
            float sc1 = (norm > MAXN) ? (MAXN / norm) : 1.0f;      // proj
            float hn  = fmaxf(norm * sc1, EPSV);
            float aa  = fminf(hn, MAXN);
            float ath = 0.5f * __logf((1.0f + aa) / (1.0f - aa));  // atanh
            float s   = sc1 * ath / hn;                            // logmap0
            *(f16x4*)&sS[row * SDS + lane * 4] =
                pack4(v.x * s, v.y * s, v.z * s, v.w * s);
        }
    }
    __syncthreads();

    const float rs0 = sRs[iA];
    const float rs1 = sRs[iB];

    // ---------- transpose-1: sS[j][k] -> sTT[k][j] (one-time) --------------
    {
        int kg = wave >> 2;   // k-group of 64
        int rb = wave & 3;    // j-block of 32
        #pragma unroll
        for (int c = 0; c < 4; ++c) {
            f16x8 v = *(const f16x8*)&sS[(rb * 32 + l31) * SDS + kg * 64 + c * 16 + hi * 8];
            #pragma unroll
            for (int e = 0; e < 8; ++e)
                sTT[(kg * 64 + c * 16 + hi * 8 + e) * SDJ + rb * 32 + l31] = v[e];
        }
    }
    __syncthreads();

    for (int layer = 0; layer < NL; ++layer) {
        // bias values for epi-2: n = nt*32 + (r&3)+8*(r>>2)+4*hi
        float bsv[16];
        #pragma unroll
        for (int r = 0; r < 16; ++r)
            bsv[r] = bs[layer * ND + nt * 32 + (r & 3) + 8 * (r >> 2) + 4 * hi];

        // ---- GEMM-1: S^T[k][i] = sum_j T^T[k][j] adj[i][j] (32x32x16).
        // A = sTT rows k (LDS), B = adjf (registers). 2 k-tiles x 1 i-col.
        f32x16 a1 = fzero16, a2 = fzero16;
        #pragma unroll
        for (int ks = 0; ks < 8; ++ks) {
            f16x8 t0 = *(const f16x8*)&sTT[((2 * kp + 0) * 32 + l31) * SDJ + ks * 16 + hi * 8];
            f16x8 t1 = *(const f16x8*)&sTT[((2 * kp + 1) * 32 + l31) * SDJ + ks * 16 + hi * 8];
            a1 = __builtin_amdgcn_mfma_f32_32x32x16_f16(t0, adjf[ks], a1, 0, 0, 0);
            a2 = __builtin_amdgcn_mfma_f32_32x32x16_f16(t1, adjf[ks], a2, 0, 0, 0);
        }
        // epi-1: S -> sS[i][k] row writes (f16x4; D rows k are 4-contig).
        {
            int i = ic1 * 32 + l31;
            #pragma unroll
            for (int g = 0; g < 4; ++g) {
                *(f16x4*)&sS[i * SDS + (2 * kp + 0) * 32 + 8 * g + 4 * hi] =
                    pack4(a1[4 * g + 0], a1[4 * g + 1], a1[4 * g + 2], a1[4 * g + 3]);
                *(f16x4*)&sS[i * SDS + (2 * kp + 1) * 32 + 8 * g + 4 * hi] =
                    pack4(a2[4 * g + 0], a2[4 * g + 1], a2[4 * g + 2], a2[4 * g + 3]);
            }
        }
        __syncthreads();   // B1: sS(S) ready

        // ---- GEMM-2: U^T[n][i] = sum_k W^T[n][k] S^T[k][i] (32x32x16).
        // A = Wt rows n (global L2, in-loop, reused x2); B = sS rows i (LDS).
        const f16* WtL = Wt + layer * ND * ND;
        f32x16 b0 = fzero16, b1v = fzero16;
        #pragma unroll
        for (int ks = 0; ks < 16; ++ks) {
            f16x8 afr = *(const f16x8*)(WtL + (nt * 32 + l31) * ND + ks * 16 + hi * 8);
            f16x8 s0 = *(const f16x8*)&sS[iA * SDS + ks * 16 + hi * 8];
            f16x8 s1 = *(const f16x8*)&sS[iB * SDS + ks * 16 + hi * 8];
            b0  = __builtin_amdgcn_mfma_f32_32x32x16_f16(afr, s0, b0, 0, 0, 0);
            b1v = __builtin_amdgcn_mfma_f32_32x32x16_f16(afr, s1, b1v, 0, 0, 0);
        }

        // ---- epi-2a: + rs_i*b_n, relu, norm partials (16 n's per lane,
        // hi-fold gives this wave's 32 n's of n-tile nt for nodes iA/iB).
        float ssq0 = 0.f, ssq1 = 0.f;
        #pragma unroll
        for (int r = 0; r < 16; ++r) {
            float u0 = fmaxf(b0[r]  + rs0 * bsv[r], 0.0f);
            float u1 = fmaxf(b1v[r] + rs1 * bsv[r], 0.0f);
            b0[r] = u0;
            b1v[r] = u1;
            ssq0 += u0 * u0;
            ssq1 += u1 * u1;
        }
        ssq0 += __shfl_xor(ssq0, 32);
        ssq1 += __shfl_xor(ssq1, 32);
        if (lane < 32) {
            sRed[iA * 8 + nt] = ssq0;
            sRed[iB * 8 + nt] = ssq1;
        }
        __syncthreads();   // B2: all 8 nt partials ready

        // ---- epi-2b: total norm, fused logmap0(proj(expmap0)) rescale,
        // write T'^T[n][i] with coalesced b16 stores (lanes = contiguous i).
        f32x4 pa = *(const f32x4*)&sRed[iA * 8];
        f32x4 pb = *(const f32x4*)&sRed[iA * 8 + 4];
        float totA = pa[0] + pa[1] + pa[2] + pa[3] + pb[0] + pb[1] + pb[2] + pb[3];
        f32x4 qa = *(const f32x4*)&sRed[iB * 8];
        f32x4 qb = *(const f32x4*)&sRed[iB * 8 + 4];
        float totB = qa[0] + qa[1] + qa[2] + qa[3] + qb[0] + qb[1] + qb[2] + qb[3];
        float nuA = sqrtf(totA);
        float nuB = sqrtf(totB);
        float sc0 = (nuA > ATHMAX) ? (ATHMAX / nuA) : 1.0f;
        float sc1 = (nuB > ATHMAX) ? (ATHMAX / nuB) : 1.0f;
        #pragma unroll
        for (int r = 0; r < 16; ++r) {
            int n = nt * 32 + (r & 3) + 8 * (r >> 2) + 4 * hi;
            sTT[n * SDJ + iA] = (f16)(b0[r] * sc0);
            sTT[n * SDJ + iB] = (f16)(b1v[r] * sc1);
        }
        __syncthreads();   // B3: sTT(T') ready for next layer
    }

    // ---------- transpose-2: sTT[n][i] -> sS[i][n] (for the head) ----------
    {
        int nb = wave & 7;    // n-block of 32
        int ig = wave >> 3;   // i-group of 64
        #pragma unroll
        for (int c = 0; c < 4; ++c) {
            f16x8 v = *(const f16x8*)&sTT[(nb * 32 + l31) * SDJ + ig * 64 + c * 16 + hi * 8];
            #pragma unroll
            for (int e = 0; e < 8; ++e)
                sS[(ig * 64 + c * 16 + hi * 8 + e) * SDS + nb * 32 + l31] = v[e];
        }
    }
    __syncthreads();

    // ---------- head: out = (out_tan @ Wout + bout) * node_mask ------------
    if (wave < 8) {
        f32x4 acc = {0.f, 0.f, 0.f, 0.f};
        #pragma unroll
        for (int ks = 0; ks < 8; ++ks) {
            f16x8 afr = *(const f16x8*)&sS[(wave * 16 + lc) * SDS + ks * 32 + lg * 8];
            f16x8 bfr = *(const f16x8*)(WoutT + lc * ND + ks * 32 + lg * 8);
            acc = __builtin_amdgcn_mfma_f32_16x16x32_f16(afr, bfr, acc, 0, 0, 0);
        }
        #pragma unroll
        for (int r = 0; r < 4; ++r) {
            int row = wave * 16 + lg * 4 + r;
            float mask = node_mask[b * NN + row];
            out[((size_t)b * NN + row) * NF + lc] = (acc[r] + bout[lc]) * mask;
        }
    }
}

extern "C" void kernel_launch(void* const* d_in, const int* in_sizes, int n_in,
                              void* d_out, int out_size, void* d_ws, size_t ws_size,
                              hipStream_t stream) {
    const float* x    = (const float*)d_in[0];
    const float* adj  = (const float*)d_in[1];
    const float* mask = (const float*)d_in[2];
    const float* Ws   = (const float*)d_in[3];
    const float* bsp  = (const float*)d_in[4];
    const float* Wout = (const float*)d_in[5];
    const float* bout = (const float*)d_in[6];

    f16* Wt    = (f16*)d_ws;                       // 3*256*256 f16 = 384KB
    f16* WoutT = Wt + NL * ND * ND;                // 16*256 f16 = 8KB

    prep_kernel<<<768, 256, 0, stream>>>(Ws, Wout, Wt, WoutT);
    hgcn_kernel<<<NB, 1024, 0, stream>>>(x, adj, mask, Wt, bsp, WoutT, bout,
                                         (float*)d_out);
}

// Round 13
// 80.311 us; speedup vs baseline: 1.5382x; 1.3877x over previous
//
#include <hip/hip_runtime.h>
#include <hip/hip_bf16.h>
#include <math.h>

// HGCN decoder, B=512, N=128, D=256, F=16, L=3, c=1 Poincare ball.
// R13 = R6 (78us baseline) with ONE isolated change: GEMM-b + epilogue-b
// replaced by the R9-verified 32x32x16 blocks (LDS reads 512->256, MFMA
// issue slots halved, adjf = 8 f16x8 registers loaded once for all layers).
// GEMM-a stays R6-verbatim: 16x16x32, wave owns n-tile, B-frag loaded
// in-loop from global (1 load per ks, reused by 8 MFMAs - the only load
// pattern that has ever hit 78us). Padded-linear LDS, cvt_pkrtz packing.

typedef _Float16 f16;
typedef f16 f16x8 __attribute__((ext_vector_type(8)));
typedef f16 f16x4 __attribute__((ext_vector_type(4)));
typedef f16 f16x2 __attribute__((ext_vector_type(2)));
typedef __fp16 fp16x2_cv __attribute__((ext_vector_type(2)));
typedef float f32x4 __attribute__((ext_vector_type(4)));
typedef float f32x16 __attribute__((ext_vector_type(16)));

#define NB 512
#define NN 128
#define ND 256
#define NF 16
#define NL 3

#define SDT 264   // sT row stride f16: 528B = 132 words, %32 = 4
#define SDV 136   // sV row stride f16: 272B =  68 words, %32 = 4

#define EPSV   1e-7f
#define MAXN   0.99999f      // 1 - 1e-5
#define ATHMAX 6.1030340f    // atanh(1 - 1e-5)

__device__ __forceinline__ f16x4 pack4(float a, float b, float c, float d) {
    fp16x2_cv lo = __builtin_amdgcn_cvt_pkrtz(a, b);
    fp16x2_cv hi = __builtin_amdgcn_cvt_pkrtz(c, d);
    f16x2 lo2, hi2;
    __builtin_memcpy(&lo2, &lo, sizeof(lo2));
    __builtin_memcpy(&hi2, &hi, sizeof(hi2));
    return __builtin_shufflevector(lo2, hi2, 0, 1, 2, 3);
}

// One-time: Wt[l][n][k] = W[l][k][n] (f16), WoutT[f][k] = Wout[k][f] (f16).
__global__ void prep_kernel(const float* __restrict__ Ws,
                            const float* __restrict__ Wout,
                            f16* __restrict__ Wt, f16* __restrict__ WoutT) {
    int idx = blockIdx.x * 256 + threadIdx.x;
    if (idx < NL * ND * ND) {
        int l = idx / (ND * ND);
        int r = idx % (ND * ND);
        int n = r >> 8;
        int k = r & 255;
        Wt[idx] = (f16)Ws[l * ND * ND + k * ND + n];
    }
    if (idx < NF * ND) {
        int f = idx >> 8;
        int k = idx & 255;
        WoutT[idx] = (f16)Wout[k * NF + f];
    }
}

__global__ __launch_bounds__(1024, 4)
void hgcn_kernel(const float* __restrict__ x,
                 const float* __restrict__ adj,
                 const float* __restrict__ node_mask,
                 const f16*  __restrict__ Wt,
                 const float* __restrict__ bs,
                 const f16*  __restrict__ WoutT,
                 const float* __restrict__ bout,
                 float* __restrict__ out) {
    __shared__ __align__(16) f16 sT[NN * SDT];   // [node m][feat k] 66KB
    __shared__ __align__(16) f16 sV[ND * SDV];   // [feat n][node m] 68KB
    __shared__ __align__(16) float sRed[NN * 4]; // 4 partials per node 2KB

    const int b    = blockIdx.x;
    const int tid  = threadIdx.x;
    const int wave = tid >> 6;   // 0..15
    const int lane = tid & 63;
    const int l31  = lane & 31;
    const int hi   = lane >> 5;  // k-half for 32x32x16 fragments
    const int lg   = lane >> 4;  // 16x16 phases
    const int lc   = lane & 15;

    // GEMM-b roles (32x32): i-col ic, n-tile pair {2*nr2, 2*nr2+1}
    const int nr2 = wave >> 2;   // 0..3
    const int ic  = wave & 3;    // 0..3

    const f32x16 fzero16 = {0.f};

    // ---------- adj B-fragments (32 VGPR, loaded once, all 3 layers) -------
    // GEMM-b: U^T[n][i] = sum_j V^T[n][j]*adj[i][j]; B[k=j][col=i] =
    // adj[ic*32+l31][j], j = ks*16 + hi*8 .. +7.   (R9-verified)
    f16x8 adjf[8];
    {
        const float* adjb = adj + (size_t)b * NN * NN;
        #pragma unroll
        for (int ks = 0; ks < 8; ++ks) {
            const float4* ap = (const float4*)(adjb + (ic * 32 + l31) * NN + ks * 16 + hi * 8);
            float4 alo = ap[0], ahi = ap[1];
            f16x4 l4 = pack4(alo.x, alo.y, alo.z, alo.w);
            f16x4 h4 = pack4(ahi.x, ahi.y, ahi.z, ahi.w);
            adjf[ks] = __builtin_shufflevector(l4, h4, 0, 1, 2, 3, 4, 5, 6, 7);
        }
    }

    // ---------- init: sT = f16(logmap0(proj(x[b]))), 8 rows per wave -------
    {
        const float4* xb = (const float4*)(x + (size_t)b * NN * ND);
        #pragma unroll
        for (int r = 0; r < 8; ++r) {
            int row = wave * 8 + r;
            float4 v = xb[row * 64 + lane];
            float ssq = v.x * v.x + v.y * v.y + v.z * v.z + v.w * v.w;
            #pragma unroll
            for (int d = 1; d < 64; d <<= 1) ssq += __shfl_xor(ssq, d);
            float norm = sqrtf(ssq);
            float sc1 = (norm > MAXN) ? (MAXN / norm) : 1.0f;      // proj
            float hn  = fmaxf(norm * sc1, EPSV);
            float aa  = fminf(hn, MAXN);
            float ath = 0.5f * __logf((1.0f + aa) / (1.0f - aa));  // atanh
            float s   = sc1 * ath / hn;                            // logmap0
            *(f16x4*)&sT[row * SDT + lane * 4] =
                pack4(v.x * s, v.y * s, v.z * s, v.w * s);
        }
    }
    __syncthreads();

    for (int layer = 0; layer < NL; ++layer) {
        const f16* WtL  = Wt + layer * ND * ND;
        const float bias = bs[layer * ND + wave * 16 + lc];  // n = wave*16+lc

        // ---- GEMM-a (R6-verbatim): V[m][n] = T @ W + b. Wave owns n-tile =
        // wave, all 8 m-tiles. A = sT row m (LDS), B = Wt row n (global/L2,
        // loaded once per ks, reused by 8 MFMAs). D rows m -> f16x4 writes.
        f32x4 acc_a[8];
        #pragma unroll
        for (int t = 0; t < 8; ++t) acc_a[t] = (f32x4){0.f, 0.f, 0.f, 0.f};

        #pragma unroll
        for (int ks = 0; ks < 8; ++ks) {
            f16x8 bfr = *(const f16x8*)(WtL + (wave * 16 + lc) * ND + ks * 32 + lg * 8);
            #pragma unroll
            for (int mt = 0; mt < 8; ++mt) {
                f16x8 afr = *(const f16x8*)&sT[(mt * 16 + lc) * SDT + ks * 32 + lg * 8];
                acc_a[mt] = __builtin_amdgcn_mfma_f32_16x16x32_f16(afr, bfr, acc_a[mt], 0, 0, 0);
            }
        }
        #pragma unroll
        for (int mt = 0; mt < 8; ++mt) {
            int n  = wave * 16 + lc;
            int m0 = mt * 16 + lg * 4;
            *(f16x4*)&sV[n * SDV + m0] =
                pack4(acc_a[mt][0] + bias, acc_a[mt][1] + bias,
                      acc_a[mt][2] + bias, acc_a[mt][3] + bias);
        }
        __syncthreads();

        // ---- GEMM-b (R9-verified 32x32): U^T[n][i], 2 n-tiles x i-col ic.
        // A = sV row n (LDS), B = adjf (registers).
        f32x16 acc_b0 = fzero16, acc_b1 = fzero16;
        #pragma unroll
        for (int ks = 0; ks < 8; ++ks) {
            f16x8 a0 = *(const f16x8*)&sV[((2 * nr2 + 0) * 32 + l31) * SDV + ks * 16 + hi * 8];
            f16x8 a1 = *(const f16x8*)&sV[((2 * nr2 + 1) * 32 + l31) * SDV + ks * 16 + hi * 8];
            acc_b0 = __builtin_amdgcn_mfma_f32_32x32x16_f16(a0, adjf[ks], acc_b0, 0, 0, 0);
            acc_b1 = __builtin_amdgcn_mfma_f32_32x32x16_f16(a1, adjf[ks], acc_b1, 0, 0, 0);
        }

        // ---- epilogue-b (R9-verified): relu + node-norm partials; 4 waves
        // (nr2=0..3) share i-col ic -> sRed[i*4+nr2].
        float ssq = 0.f;
        #pragma unroll
        for (int r = 0; r < 16; ++r) {
            float v0 = fmaxf(acc_b0[r], 0.0f);
            float v1 = fmaxf(acc_b1[r], 0.0f);
            acc_b0[r] = v0;
            acc_b1[r] = v1;
            ssq += v0 * v0 + v1 * v1;
        }
        ssq += __shfl_xor(ssq, 32);   // fold the two row-halves (same col i)
        if (lane < 32) sRed[(ic * 32 + l31) * 4 + nr2] = ssq;
        __syncthreads();

        f32x4 p = *(const f32x4*)&sRed[(ic * 32 + l31) * 4];
        float tot = p[0] + p[1] + p[2] + p[3];
        float nu = sqrtf(tot);
        float scale = (nu > ATHMAX) ? (ATHMAX / nu) : 1.0f;

        // fused logmap0(proj(expmap0(u))) = u * min(1, ATHMAX/||u||) -> sT.
        {
            int i = ic * 32 + l31;
            #pragma unroll
            for (int g = 0; g < 4; ++g) {
                int n0 = (2 * nr2 + 0) * 32 + 8 * g + 4 * hi;
                int n1 = (2 * nr2 + 1) * 32 + 8 * g + 4 * hi;
                *(f16x4*)&sT[i * SDT + n0] =
                    pack4(acc_b0[4 * g + 0] * scale, acc_b0[4 * g + 1] * scale,
                          acc_b0[4 * g + 2] * scale, acc_b0[4 * g + 3] * scale);
                *(f16x4*)&sT[i * SDT + n1] =
                    pack4(acc_b1[4 * g + 0] * scale, acc_b1[4 * g + 1] * scale,
                          acc_b1[4 * g + 2] * scale, acc_b1[4 * g + 3] * scale);
            }
        }
        __syncthreads();
    }

    // ---------- head (R6-verbatim): out = (tan @ Wout + bout) * mask -------
    if (wave < 8) {
        f32x4 acc = {0.f, 0.f, 0.f, 0.f};
        #pragma unroll
        for (int ks = 0; ks < 8; ++ks) {
            f16x8 afr = *(const f16x8*)&sT[(wave * 16 + lc) * SDT + ks * 32 + lg * 8];
            f16x8 bfr = *(const f16x8*)(WoutT + lc * ND + ks * 32 + lg * 8);
            acc = __builtin_amdgcn_mfma_f32_16x16x32_f16(afr, bfr, acc, 0, 0, 0);
        }
        #pragma unroll
        for (int r = 0; r < 4; ++r) {
            int row = wave * 16 + lg * 4 + r;
            float mask = node_mask[b * NN + row];
            out[((size_t)b * NN + row) * NF + lc] = (acc[r] + bout[lc]) * mask;
        }
    }
}

extern "C" void kernel_launch(void* const* d_in, const int* in_sizes, int n_in,
                              void* d_out, int out_size, void* d_ws, size_t ws_size,
                              hipStream_t stream) {
    const float* x    = (const float*)d_in[0];
    const float* adj  = (const float*)d_in[1];
    const float* mask = (const float*)d_in[2];
    const float* Ws   = (const float*)d_in[3];
    const float* bsp  = (const float*)d_in[4];
    const float* Wout = (const float*)d_in[5];
    const float* bout = (const float*)d_in[6];

    f16* Wt    = (f16*)d_ws;                       // 3*256*256 f16 = 384KB
    f16* WoutT = Wt + NL * ND * ND;                // 16*256 f16 = 8KB

    prep_kernel<<<768, 256, 0, stream>>>(Ws, Wout, Wt, WoutT);
    hgcn_kernel<<<NB, 1024, 0, stream>>>(x, adj, mask, Wt, bsp, WoutT, bout,
                                         (float*)d_out);
}